// Round 1
// baseline (581.761 us; speedup 1.0000x reference)
//
#include <hip/hip_runtime.h>
#include <hip/hip_bf16.h>
#include <stdint.h>

// Problem constants
#define NN      1000000      // NUM_NODES
#define DD      128          // MEM_DIM == MSG_DIM
#define BT      262144       // batch B
#define W_ELEMS (384 * 128)  // per weight matrix

typedef __attribute__((ext_vector_type(8))) short bf16x8;  // 8 bf16 in 4 VGPRs
typedef __attribute__((ext_vector_type(4))) float f32x4;

__device__ __forceinline__ unsigned short f2bf(float f) {
    union { float f; uint32_t u; } c; c.f = f;
    uint32_t u = c.u + 0x7FFFu + ((c.u >> 16) & 1u);  // RNE
    return (unsigned short)(u >> 16);
}

__device__ __forceinline__ float sigmoid_f(float x) {
    return 1.0f / (1.0f + __expf(-x));
}
__device__ __forceinline__ float tanh_f(float x) {
    return 2.0f / (1.0f + __expf(-2.0f * x)) - 1.0f;
}

// ---------------------------------------------------------------------------
// Kernel 1: init winner[] to -1; convert both weight matrices to bf16 in ws.
__global__ __launch_bounds__(256) void k_init(int* __restrict__ winner,
                                              const float* __restrict__ Wih,
                                              const float* __restrict__ Whh,
                                              unsigned short* __restrict__ wbf) {
    int i = blockIdx.x * 256 + threadIdx.x;
    if (i < NN) winner[i] = -1;
    if (i < 2 * W_ELEMS) {
        float v = (i < W_ELEMS) ? Wih[i] : Whh[i - W_ELEMS];
        wbf[i] = f2bf(v);
    }
}

// ---------------------------------------------------------------------------
// Kernel 2: last-occurrence-wins winner per node.
__global__ __launch_bounds__(256) void k_winner(const int* __restrict__ node_ids,
                                                int* __restrict__ winner) {
    int i = blockIdx.x * 256 + threadIdx.x;
    if (i < BT) atomicMax(&winner[node_ids[i]], i);
}

// ---------------------------------------------------------------------------
// Kernel 3: copy memory rows not owned by a winner; write last_update for all.
__global__ __launch_bounds__(256) void k_copy(const float4* __restrict__ mem_in,
                                              const float* __restrict__ lu_in,
                                              const float* __restrict__ ts,
                                              const int* __restrict__ winner,
                                              float4* __restrict__ mem_out,
                                              float* __restrict__ lu_out) {
    const long NV4 = (long)NN * 32;        // 32 float4 per row
    const long TOTAL = NV4 + NN;
    long stride = (long)gridDim.x * 256;
    for (long i = blockIdx.x * 256L + threadIdx.x; i < TOTAL; i += stride) {
        if (i < NV4) {
            int node = (int)(i >> 5);
            if (winner[node] < 0) mem_out[i] = mem_in[i];
        } else {
            int v = (int)(i - NV4);
            int w = winner[v];
            lu_out[v] = (w >= 0) ? ts[w] : lu_in[v];
        }
    }
}

// ---------------------------------------------------------------------------
// Kernel 4: fused gather + GRU cell (bf16 MFMA) + gated scatter.
// Block = 256 threads = 4 waves; each wave owns 16 batch rows.
// mfma_f32_16x16x32_bf16: A[r][k]: r=lane&15, k=8*(lane>>4)+e (contiguous 8)
//                         B[k][n]: n=lane&15, k=8*(lane>>4)+e
//                         D[r][c]: c=lane&15, r=4*(lane>>4)+q
__global__ __launch_bounds__(256) void k_gru(const float* __restrict__ memory,
                                             const float* __restrict__ messages,
                                             const unsigned short* __restrict__ wbf,
                                             const float* __restrict__ b_ih,
                                             const float* __restrict__ b_hh,
                                             const int* __restrict__ node_ids,
                                             const int* __restrict__ winner,
                                             float* __restrict__ out_mem) {
    __shared__ int s_nid[64];
    __shared__ int s_write[64];

    const int tid = threadIdx.x;
    const int blockRow = blockIdx.x * 64;

    if (tid < 64) {
        int brow = blockRow + tid;
        int nid = node_ids[brow];
        s_nid[tid] = nid;
        s_write[tid] = (winner[nid] == brow) ? 1 : 0;
    }
    __syncthreads();

    const int wave = tid >> 6;
    const int lane = tid & 63;
    const int l15 = lane & 15;
    const int khalf = lane >> 4;       // 0..3
    const int rowbase = wave * 16;     // row offset within block
    const int arow = rowbase + l15;    // this lane's A-fragment row (0..63)

    const float* xrow = messages + (size_t)(blockRow + arow) * DD;
    const float* hrow = memory + (size_t)s_nid[arow] * DD;

    // Load & convert A fragments for all 4 K-steps (messages and gathered h)
    bf16x8 ax[4], ah[4];
#pragma unroll
    for (int ks = 0; ks < 4; ++ks) {
        int koff = ks * 32 + khalf * 8;
        float4 f0 = *(const float4*)(xrow + koff);
        float4 f1 = *(const float4*)(xrow + koff + 4);
        bf16x8 a;
        a[0] = (short)f2bf(f0.x); a[1] = (short)f2bf(f0.y);
        a[2] = (short)f2bf(f0.z); a[3] = (short)f2bf(f0.w);
        a[4] = (short)f2bf(f1.x); a[5] = (short)f2bf(f1.y);
        a[6] = (short)f2bf(f1.z); a[7] = (short)f2bf(f1.w);
        ax[ks] = a;
        f0 = *(const float4*)(hrow + koff);
        f1 = *(const float4*)(hrow + koff + 4);
        bf16x8 b;
        b[0] = (short)f2bf(f0.x); b[1] = (short)f2bf(f0.y);
        b[2] = (short)f2bf(f0.z); b[3] = (short)f2bf(f0.w);
        b[4] = (short)f2bf(f1.x); b[5] = (short)f2bf(f1.y);
        b[6] = (short)f2bf(f1.z); b[7] = (short)f2bf(f1.w);
        ah[ks] = b;
    }

    const unsigned short* Wih = wbf;
    const unsigned short* Whh = wbf + W_ELEMS;

    // 8 chunks of 16 hidden columns each
    for (int jc = 0; jc < 8; ++jc) {
        const int j0 = jc * 16;
        f32x4 acc_ir = {0.f,0.f,0.f,0.f}, acc_iz = acc_ir, acc_in = acc_ir;
        f32x4 acc_hr = acc_ir, acc_hz = acc_ir, acc_hn = acc_ir;

        const int wr = j0 + l15;  // weight row within gate block (0..127)
#pragma unroll
        for (int ks = 0; ks < 4; ++ks) {
            const int k = ks * 32 + khalf * 8;
            bf16x8 b_ir = *(const bf16x8*)(Wih + (size_t)(wr      ) * DD + k);
            bf16x8 b_iz = *(const bf16x8*)(Wih + (size_t)(wr + 128) * DD + k);
            bf16x8 b_in = *(const bf16x8*)(Wih + (size_t)(wr + 256) * DD + k);
            bf16x8 b_hr = *(const bf16x8*)(Whh + (size_t)(wr      ) * DD + k);
            bf16x8 b_hz = *(const bf16x8*)(Whh + (size_t)(wr + 128) * DD + k);
            bf16x8 b_hn = *(const bf16x8*)(Whh + (size_t)(wr + 256) * DD + k);
            acc_ir = __builtin_amdgcn_mfma_f32_16x16x32_bf16(ax[ks], b_ir, acc_ir, 0, 0, 0);
            acc_iz = __builtin_amdgcn_mfma_f32_16x16x32_bf16(ax[ks], b_iz, acc_iz, 0, 0, 0);
            acc_in = __builtin_amdgcn_mfma_f32_16x16x32_bf16(ax[ks], b_in, acc_in, 0, 0, 0);
            acc_hr = __builtin_amdgcn_mfma_f32_16x16x32_bf16(ah[ks], b_hr, acc_hr, 0, 0, 0);
            acc_hz = __builtin_amdgcn_mfma_f32_16x16x32_bf16(ah[ks], b_hz, acc_hz, 0, 0, 0);
            acc_hn = __builtin_amdgcn_mfma_f32_16x16x32_bf16(ah[ks], b_hn, acc_hn, 0, 0, 0);
        }

        const int jcol = j0 + l15;
        const float bir = b_ih[jcol], biz = b_ih[128 + jcol], bin = b_ih[256 + jcol];
        const float bhr = b_hh[jcol], bhz = b_hh[128 + jcol], bhn = b_hh[256 + jcol];

#pragma unroll
        for (int q = 0; q < 4; ++q) {
            const int rlocal = rowbase + khalf * 4 + q;  // C/D row within block
            float r = sigmoid_f(acc_ir[q] + bir + acc_hr[q] + bhr);
            float z = sigmoid_f(acc_iz[q] + biz + acc_hz[q] + bhz);
            float n = tanh_f(acc_in[q] + bin + r * (acc_hn[q] + bhn));
            int nid = s_nid[rlocal];
            float h = memory[(size_t)nid * DD + jcol];
            float hnew = (1.0f - z) * n + z * h;
            if (s_write[rlocal]) out_mem[(size_t)nid * DD + jcol] = hnew;
        }
    }
}

// ---------------------------------------------------------------------------
extern "C" void kernel_launch(void* const* d_in, const int* in_sizes, int n_in,
                              void* d_out, int out_size, void* d_ws, size_t ws_size,
                              hipStream_t stream) {
    const float* memory      = (const float*)d_in[0];
    const float* last_update = (const float*)d_in[1];
    const float* messages    = (const float*)d_in[2];
    const float* timestamps  = (const float*)d_in[3];
    const float* W_ih        = (const float*)d_in[4];
    const float* W_hh        = (const float*)d_in[5];
    const float* b_ih        = (const float*)d_in[6];
    const float* b_hh        = (const float*)d_in[7];
    const int*   node_ids    = (const int*)d_in[8];

    float* out_mem = (float*)d_out;
    float* out_lu  = out_mem + (size_t)NN * DD;

    // ws layout: [0, 4MB) winner int32[NN]; [4MB, +192KB) bf16 weights
    int* winner = (int*)d_ws;
    unsigned short* wbf = (unsigned short*)((char*)d_ws + (4u << 20));

    k_init<<<(NN + 255) / 256, 256, 0, stream>>>(winner, W_ih, W_hh, wbf);
    k_winner<<<BT / 256, 256, 0, stream>>>(node_ids, winner);
    k_copy<<<4096, 256, 0, stream>>>((const float4*)memory, last_update, timestamps,
                                     winner, (float4*)out_mem, out_lu);
    k_gru<<<BT / 64, 256, 0, stream>>>(memory, messages, wbf, b_ih, b_hh,
                                       node_ids, winner, out_mem);
}

// Round 2
// 331.346 us; speedup vs baseline: 1.7557x; 1.7557x over previous
//
#include <hip/hip_runtime.h>
#include <stdint.h>

// Problem constants
#define NN   1000000      // NUM_NODES
#define DD   128          // MEM_DIM == MSG_DIM
#define BT   262144       // batch B
#define TR   32           // rows per LDS tile
#define NT   8            // tiles per block
#define RPB  (TR * NT)    // 256 batch rows per block
#define GRID_GRU (BT / RPB)   // 1024 blocks

typedef __attribute__((ext_vector_type(8))) short bf16x8;  // 8 bf16 in 4 VGPRs
typedef __attribute__((ext_vector_type(4))) float f32x4;

__device__ __forceinline__ unsigned short f2bf(float f) {
    union { float f; uint32_t u; } c; c.f = f;
    uint32_t u = c.u + 0x7FFFu + ((c.u >> 16) & 1u);  // RNE
    return (unsigned short)(u >> 16);
}
__device__ __forceinline__ float bf2f(unsigned short s) {
    union { uint32_t u; float f; } c; c.u = ((uint32_t)s) << 16;
    return c.f;
}
__device__ __forceinline__ float sigmoid_f(float x) {
    return 1.0f / (1.0f + __expf(-x));
}
__device__ __forceinline__ float tanh_f(float x) {
    return 2.0f / (1.0f + __expf(-2.0f * x)) - 1.0f;
}
__device__ __forceinline__ bf16x8 cvt8(float4 a, float4 b) {
    bf16x8 v;
    v[0] = (short)f2bf(a.x); v[1] = (short)f2bf(a.y);
    v[2] = (short)f2bf(a.z); v[3] = (short)f2bf(a.w);
    v[4] = (short)f2bf(b.x); v[5] = (short)f2bf(b.y);
    v[6] = (short)f2bf(b.z); v[7] = (short)f2bf(b.w);
    return v;
}

// ---------------------------------------------------------------------------
// last-occurrence-wins winner per node (winner[] pre-set to -1 via memset 0xFF)
__global__ __launch_bounds__(256) void k_winner(const int* __restrict__ node_ids,
                                                int* __restrict__ winner) {
    int i = blockIdx.x * 256 + threadIdx.x;
    if (i < BT) atomicMax(&winner[node_ids[i]], i);
}

// ---------------------------------------------------------------------------
// copy memory rows not owned by a winner; write last_update for all nodes.
__global__ __launch_bounds__(256) void k_copy(const float4* __restrict__ mem_in,
                                              const float* __restrict__ lu_in,
                                              const float* __restrict__ ts,
                                              const int* __restrict__ winner,
                                              float4* __restrict__ mem_out,
                                              float* __restrict__ lu_out) {
    const long NV4 = (long)NN * 32;        // 32 float4 per row
    const long TOTAL = NV4 + NN;
    long stride = (long)gridDim.x * 256;
    for (long i = blockIdx.x * 256L + threadIdx.x; i < TOTAL; i += stride) {
        if (i < NV4) {
            int node = (int)(i >> 5);
            if (winner[node] < 0) mem_out[i] = mem_in[i];
        } else {
            int v = (int)(i - NV4);
            int w = winner[v];
            lu_out[v] = (w >= 0) ? ts[w] : lu_in[v];
        }
    }
}

// ---------------------------------------------------------------------------
// Fused gather + GRU (bf16 MFMA) + gated scatter.
// 512 threads = 8 waves. Wave w owns output cols [16w,16w+16) with ALL 24
// weight B-fragments register-resident (loaded once). Block loops over 8
// row-tiles of 32 rows staged in double-buffered, XOR-swizzled LDS (bf16).
// mfma_f32_16x16x32_bf16 layout: A[r][k]: r=lane&15, k=8*(lane>>4)+e
//                                B[k][n]: n=lane&15, same k
//                                D[r][c]: c=lane&15, r=4*(lane>>4)+q
__global__ __launch_bounds__(512, 2) void k_gru(const float* __restrict__ memory,
                                                const float* __restrict__ messages,
                                                const float* __restrict__ W_ih,
                                                const float* __restrict__ W_hh,
                                                const float* __restrict__ b_ih,
                                                const float* __restrict__ b_hh,
                                                const int* __restrict__ node_ids,
                                                const int* __restrict__ winner,
                                                float* __restrict__ out_mem) {
    __shared__ unsigned short x_lds[2][TR * DD];   // 2 x 8 KB, swizzled
    __shared__ unsigned short h_lds[2][TR * DD];   // 2 x 8 KB, swizzled
    __shared__ int s_nid[RPB];
    __shared__ unsigned char s_win[RPB];

    const int tid = threadIdx.x;
    const int rowBase = blockIdx.x * RPB;

    // preload node ids + winner flags for all 256 rows of this block
    for (int i = tid; i < RPB; i += 512) {
        int brow = rowBase + i;
        int nid = node_ids[brow];
        s_nid[i] = nid;
        s_win[i] = (winner[nid] == brow) ? 1 : 0;
    }
    __syncthreads();

    const int lane  = tid & 63;
    const int wave  = tid >> 6;
    const int l15   = lane & 15;
    const int khalf = lane >> 4;            // 0..3
    const int jcol  = wave * 16 + l15;      // this lane's output column

    // ---- weight fragments (fp32 -> bf16), register-resident: 24 x bf16x8 ----
    bf16x8 wf[6][4];
#pragma unroll
    for (int g = 0; g < 3; ++g) {
#pragma unroll
        for (int ks = 0; ks < 4; ++ks) {
            const float* p = W_ih + (size_t)(g * 128 + jcol) * DD + ks * 32 + khalf * 8;
            wf[g][ks] = cvt8(*(const float4*)p, *(const float4*)(p + 4));
            const float* q = W_hh + (size_t)(g * 128 + jcol) * DD + ks * 32 + khalf * 8;
            wf[3 + g][ks] = cvt8(*(const float4*)q, *(const float4*)(q + 4));
        }
    }
    const float bir = b_ih[jcol], biz = b_ih[128 + jcol], bin = b_ih[256 + jcol];
    const float bhr = b_hh[jcol], bhz = b_hh[128 + jcol], bhn = b_hh[256 + jcol];

    // ---- staging geometry: thread -> (row sr, 8-col chunk sc8), swizzled ----
    const int sr  = tid >> 4;               // 0..31
    const int sc8 = (tid & 15) * 8;         // 0..120
    const int ldsOff = sr * 256 + ((sc8 * 2) ^ ((sr & 7) << 4));

    // prefetch tile 0 into registers
    float4 px0, px1, ph0, ph1;
    {
        const float* xp = messages + (size_t)(rowBase + sr) * DD + sc8;
        px0 = ((const float4*)xp)[0]; px1 = ((const float4*)xp)[1];
        const float* hp = memory + (size_t)s_nid[sr] * DD + sc8;
        ph0 = ((const float4*)hp)[0]; ph1 = ((const float4*)hp)[1];
    }

#pragma unroll 1
    for (int t = 0; t < NT; ++t) {
        const int buf = t & 1;
        // stage current tile (convert + swizzled LDS write)
        *(bf16x8*)((char*)(&x_lds[buf][0]) + ldsOff) = cvt8(px0, px1);
        *(bf16x8*)((char*)(&h_lds[buf][0]) + ldsOff) = cvt8(ph0, ph1);
        // issue next tile's global loads (stay in flight across the barrier)
        if (t + 1 < NT) {
            int r = (t + 1) * TR + sr;
            const float* xp = messages + (size_t)(rowBase + r) * DD + sc8;
            px0 = ((const float4*)xp)[0]; px1 = ((const float4*)xp)[1];
            const float* hp = memory + (size_t)s_nid[r] * DD + sc8;
            ph0 = ((const float4*)hp)[0]; ph1 = ((const float4*)hp)[1];
        }
        // LDS-visible barrier that does NOT drain vmcnt (prefetch stays live)
        asm volatile("s_waitcnt lgkmcnt(0)" ::: "memory");
        __builtin_amdgcn_sched_barrier(0);
        __builtin_amdgcn_s_barrier();
        __builtin_amdgcn_sched_barrier(0);

        // compute: two 16-row sub-tiles
#pragma unroll
        for (int sub = 0; sub < 2; ++sub) {
            const int arow = sub * 16 + l15;
            const char* xb = (const char*)(&x_lds[buf][0]) + arow * 256;
            const char* hb = (const char*)(&h_lds[buf][0]) + arow * 256;
            const int aswz = (arow & 7) << 4;
            bf16x8 ax[4], ah[4];
#pragma unroll
            for (int ks = 0; ks < 4; ++ks) {
                const int cb = (ks * 64 + khalf * 16) ^ aswz;
                ax[ks] = *(const bf16x8*)(xb + cb);
                ah[ks] = *(const bf16x8*)(hb + cb);
            }
            f32x4 a_ir = {0.f,0.f,0.f,0.f}, a_iz = a_ir, a_in = a_ir;
            f32x4 a_hr = a_ir, a_hz = a_ir, a_hn = a_ir;
#pragma unroll
            for (int ks = 0; ks < 4; ++ks) {
                a_ir = __builtin_amdgcn_mfma_f32_16x16x32_bf16(ax[ks], wf[0][ks], a_ir, 0, 0, 0);
                a_iz = __builtin_amdgcn_mfma_f32_16x16x32_bf16(ax[ks], wf[1][ks], a_iz, 0, 0, 0);
                a_in = __builtin_amdgcn_mfma_f32_16x16x32_bf16(ax[ks], wf[2][ks], a_in, 0, 0, 0);
                a_hr = __builtin_amdgcn_mfma_f32_16x16x32_bf16(ah[ks], wf[3][ks], a_hr, 0, 0, 0);
                a_hz = __builtin_amdgcn_mfma_f32_16x16x32_bf16(ah[ks], wf[4][ks], a_hz, 0, 0, 0);
                a_hn = __builtin_amdgcn_mfma_f32_16x16x32_bf16(ah[ks], wf[5][ks], a_hn, 0, 0, 0);
            }
#pragma unroll
            for (int q = 0; q < 4; ++q) {
                const int rl = sub * 16 + khalf * 4 + q;   // row within tile
                const int tr = t * TR + rl;                // row within block
                float rg = sigmoid_f(a_ir[q] + bir + a_hr[q] + bhr);
                float zg = sigmoid_f(a_iz[q] + biz + a_hz[q] + bhz);
                float ng = tanh_f(a_in[q] + bin + rg * (a_hn[q] + bhn));
                unsigned short hu = *(const unsigned short*)(
                    (const char*)(&h_lds[buf][0]) + rl * 256 + ((jcol * 2) ^ ((rl & 7) << 4)));
                float h = bf2f(hu);
                float hnew = (1.0f - zg) * ng + zg * h;
                if (s_win[tr]) out_mem[(size_t)s_nid[tr] * DD + jcol] = hnew;
            }
        }
        // no trailing barrier: double-buffered LDS + lgkmcnt(0)-before-barrier
        // makes the single per-tile barrier sufficient.
    }
}

// ---------------------------------------------------------------------------
extern "C" void kernel_launch(void* const* d_in, const int* in_sizes, int n_in,
                              void* d_out, int out_size, void* d_ws, size_t ws_size,
                              hipStream_t stream) {
    const float* memory      = (const float*)d_in[0];
    const float* last_update = (const float*)d_in[1];
    const float* messages    = (const float*)d_in[2];
    const float* timestamps  = (const float*)d_in[3];
    const float* W_ih        = (const float*)d_in[4];
    const float* W_hh        = (const float*)d_in[5];
    const float* b_ih        = (const float*)d_in[6];
    const float* b_hh        = (const float*)d_in[7];
    const int*   node_ids    = (const int*)d_in[8];

    float* out_mem = (float*)d_out;
    float* out_lu  = out_mem + (size_t)NN * DD;

    int* winner = (int*)d_ws;

    // winner[i] = -1 for all nodes
    hipMemsetAsync(winner, 0xFF, (size_t)NN * sizeof(int), stream);
    k_winner<<<BT / 256, 256, 0, stream>>>(node_ids, winner);
    k_copy<<<4096, 256, 0, stream>>>((const float4*)memory, last_update, timestamps,
                                     winner, (float4*)out_mem, out_lu);
    k_gru<<<GRID_GRU, 512, 0, stream>>>(memory, messages, W_ih, W_hh, b_ih, b_hh,
                                        node_ids, winner, out_mem);
}